// Round 19
// baseline (115.071 us; speedup 1.0000x reference)
//
#include <hip/hip_runtime.h>
#include <math.h>

#define NB 4
#define NP 144
#define NBP (NB*NP)   // 576 (b,p) problems
#define KW 9
#define CIN 32
#define NC 32
#define NK 288
#define ND 16
#define NDH 8
#define NCND 512
#define EPSI 1e-7f

// ---- pass-split pipeline (r19): 3 heavy kernels (k halved, 1152 blocks)
//      + 3 combine kernels; pass boundary == kernel boundary (NO inter-block
//      sync, no residency assumption — r18's pair-spin deadlocked).
#define NTS 192       // 3 waves
#define KH  144       // k per heavy block
#define KPTS 24       // k per thread (6 slices)
#define NGR 3
#define PART_F 1056   // m1 512 + m2 512 + r0 32
#define STATS_F 1056  // mu 512 + ivar 512 + A 32
#define WS_PART_FLOATS ((size_t)2*NBP*PART_F)
#define WS_NEEDED ((WS_PART_FLOATS + (size_t)NBP*STATS_F) * 4)

// ---- fallback = r11 verbatim (best single-kernel: 97.7us) ----
#define NT 256
#define KPT 36
#define NRED 2

typedef float v2f __attribute__((ext_vector_type(2)));

__device__ __forceinline__ v2f mkv2(float a, float b) { v2f r; r[0] = a; r[1] = b; return r; }

template<int CTRL>
__device__ __forceinline__ float dppf(float x) {
    return __int_as_float(__builtin_amdgcn_update_dpp(
        0, __float_as_int(x), CTRL, 0xF, 0xF, true));
}
// 0xB1=quad_perm xor1 ; 0x4E=quad_perm xor2 ; 0x141=row_half_mirror ; 0x140=row_mirror
__device__ __forceinline__ float swz16(float x) {
    return __int_as_float(__builtin_amdgcn_ds_swizzle(__float_as_int(x), 0x401F));
}
__device__ __forceinline__ float red16_max(float x) {
    x = fmaxf(x, dppf<0xB1>(x));
    x = fmaxf(x, dppf<0x4E>(x));
    x = fmaxf(x, dppf<0x141>(x));
    x = fmaxf(x, dppf<0x140>(x));
    return x;
}
__device__ __forceinline__ float red16_sum(float x) {
    x += dppf<0xB1>(x);
    x += dppf<0x4E>(x);
    x += dppf<0x141>(x);
    x += dppf<0x140>(x);
    return x;
}

__device__ __forceinline__ int sw4(int c, int j) { return j ^ ((c >> 1) & 3); }

__device__ __forceinline__ void load16(const float* src, float* dst) {
    const float4* s4 = (const float4*)src;
    *(float4*)&dst[0]  = s4[0];
    *(float4*)&dst[4]  = s4[1];
    *(float4*)&dst[8]  = s4[2];
    *(float4*)&dst[12] = s4[3];
}
__device__ __forceinline__ void load16v(const float* src, v2f* dst) {
    const float4* s4 = (const float4*)src;
    #pragma unroll
    for (int q = 0; q < 4; ++q) {
        const float4 tq = s4[q];
        dst[q*2+0] = mkv2(tq.x, tq.y);
        dst[q*2+1] = mkv2(tq.z, tq.w);
    }
}

// vote pairs: v[i*2+p] = {vote[i*4+2p], vote[i*4+2p+1]}
__device__ __forceinline__ void vote44v(const float* pr, const v2f* wr2, v2f* v) {
    #pragma unroll
    for (int i = 0; i < 4; ++i) {
        const v2f p0 = mkv2(pr[i*4+0], pr[i*4+0]);
        const v2f p1 = mkv2(pr[i*4+1], pr[i*4+1]);
        const v2f p2 = mkv2(pr[i*4+2], pr[i*4+2]);
        const v2f p3 = mkv2(pr[i*4+3], pr[i*4+3]);
        #pragma unroll
        for (int p = 0; p < 2; ++p) {
            v2f acc = p0 * wr2[0*2+p];
            acc += p1 * wr2[1*2+p];
            acc += p2 * wr2[2*2+p];
            acc += p3 * wr2[3*2+p];
            v[i*2+p] = acc;
        }
    }
}

// =====================================================================
// HEAVY KERNEL: one k-half of one pass; writes 1056-float partial to ws
// =====================================================================
template<bool FIRST>
__global__ __launch_bounds__(NTS) void convcaps_pass(
    const float* __restrict__ g_act,    // [B,196,32]
    const float* __restrict__ g_pose,   // [B,196,32,16]
    const float* __restrict__ g_W,      // [288,32,16]
    const int*   __restrict__ g_cpm,    // [144,9]
    const float* __restrict__ g_stats,  // [576][1056] (mu,ivar,A) — unused if FIRST
    float* __restrict__ g_part)         // [1152][1056]
{
    __shared__ float s_pose[KH][ND];       // 9216 B
    __shared__ float s_act[KH];            // 576 B
    __shared__ float s_m1[NGR][NC][ND];    // 6144 B
    __shared__ float s_m2[NGR][NC][ND];    // 6144 B
    __shared__ float s_r0[NGR][NC];        // 384 B  ~= 22.5 KB

    const int bid  = blockIdx.x;
    const int g    = bid / NBP;            // k-half
    const int bp   = bid - g * NBP;
    const int b    = bp / NP;
    const int p    = bp - b * NP;
    const int t    = threadIdx.x;
    const int c    = t & 31;
    const int sl   = t >> 5;               // 0..5
    const int wave = t >> 6;
    const int lane = t & 63;

    // ---- gather this block's k-half ----
    {
        const int* cpm = g_cpm + p * KW;
        const float4* pb4 = (const float4*)(g_pose + (size_t)b * (196 * CIN * ND));
        float4* sp4 = (float4*)&s_pose[0][0];
        #pragma unroll 1
        for (int i4 = t; i4 < KH * 4; i4 += NTS) {        // 576 float4
            const int kk  = g * KH + (i4 >> 2);
            const int w   = kk >> 5;
            const int rem = ((kk & 31) << 2) | (i4 & 3);
            sp4[i4] = pb4[(size_t)cpm[w] * 128 + rem];
        }
        const float* ab = g_act + (size_t)b * (196 * CIN);
        if (t < KH) {
            const int kk = g * KH + t;
            s_act[t] = ab[cpm[kk >> 5] * CIN + (kk & 31)];
        }
    }

    // ---- hoisted per-c stats (E-passes) ----
    const float L2E = 1.4426950408889634f;
    v2f iv2v[NDH], h2n2v[NDH];
    float A2 = 0.0f;
    if (!FIRST) {
        const float* st = g_stats + (size_t)bp * STATS_F;
        float gq2 = 0.0f;
        #pragma unroll
        for (int e = 0; e < NDH; ++e) {
            float ivs[2], hns[2];
            #pragma unroll
            for (int u = 0; u < 2; ++u) {
                const float mu  = st[c * ND + 2*e + u];
                const float iv2 = st[NCND + c * ND + 2*e + u] * (0.5f * L2E);
                ivs[u] = iv2;
                const float h = iv2 * mu;
                hns[u] = -(h + h);
                gq2 = fmaf(h, mu, gq2);
            }
            iv2v[e]  = mkv2(ivs[0], ivs[1]);
            h2n2v[e] = mkv2(hns[0], hns[1]);
        }
        A2 = fmaf(L2E, st[2 * NCND + c], -gq2);
    }
    __syncthreads();

    const int    k0  = sl * KPTS;
    const float* wp0 = g_W + (size_t)((g * KH + k0) * NC + c) * ND;

    float r0 = 0.0f;
    v2f m1v[NDH], m2v[NDH];
    #pragma unroll
    for (int d = 0; d < NDH; ++d) { m1v[d] = mkv2(0,0); m2v[d] = mkv2(0,0); }

    const float* wp = wp0;
    #pragma unroll 1
    for (int jj = 0; jj < KPTS; jj += 2, wp += 2 * NCND) {
        float pr[ND]; v2f wr[NDH];
        v2f va[NDH], vb[NDH];
        load16(&s_pose[k0 + jj][0], pr);
        load16v(wp, wr);
        vote44v(pr, wr, va);
        load16(&s_pose[k0 + jj + 1][0], pr);
        load16v(wp + NCND, wr);
        vote44v(pr, wr, vb);

        const float2 a2 = *(const float2*)&s_act[k0 + jj];
        float rpa, rpb;
        if (FIRST) {
            rpa = a2.x * (1.0f / 32.0f);
            rpb = a2.y * (1.0f / 32.0f);
        } else {
            v2f qa2 = mkv2(0,0), qb2 = mkv2(0,0);
            #pragma unroll
            for (int e = 0; e < NDH; ++e) {
                qa2 += (iv2v[e] * va[e] + h2n2v[e]) * va[e];
                qb2 += (iv2v[e] * vb[e] + h2n2v[e]) * vb[e];
            }
            const float la = A2 - (qa2[0] + qa2[1]);
            const float lb = A2 - (qb2[0] + qb2[1]);

            const float ma = red16_max(la);
            const float mb = red16_max(lb);
            const float ea = __builtin_amdgcn_exp2f(la - ma);
            const float eb = __builtin_amdgcn_exp2f(lb - mb);
            const float sa = red16_sum(ea);
            const float sb = red16_sum(eb);
            const float mao = swz16(ma);
            const float sao = swz16(sa);
            const float mbo = swz16(mb);
            const float sbo = swz16(sb);
            const float Ma = fmaxf(ma, mao);
            const float Mb = fmaxf(mb, mbo);
            const float wa = __builtin_amdgcn_exp2f(ma - Ma);
            const float wb = __builtin_amdgcn_exp2f(mb - Mb);
            const float Sa = fmaf(sao, __builtin_amdgcn_exp2f(mao - Ma), sa * wa);
            const float Sb = fmaf(sbo, __builtin_amdgcn_exp2f(mbo - Mb), sb * wb);
            rpa = ea * wa * __builtin_amdgcn_rcpf(Sa) * a2.x;
            rpb = eb * wb * __builtin_amdgcn_rcpf(Sb) * a2.y;
        }

        r0 += rpa + rpb;
        const v2f rpav = mkv2(rpa, rpa), rpbv = mkv2(rpb, rpb);
        #pragma unroll
        for (int d = 0; d < NDH; ++d) {
            const v2f rva = rpav * va[d];
            const v2f rvb = rpbv * vb[d];
            m1v[d] += rva + rvb;
            m2v[d] += rva * va[d] + rvb * vb[d];
        }
    }

    // ---- block reduce -> linear partial to global ----
    float m1[ND], m2[ND];
    #pragma unroll
    for (int e = 0; e < NDH; ++e) {
        m1[2*e] = m1v[e][0]; m1[2*e+1] = m1v[e][1];
        m2[2*e] = m2v[e][0]; m2[2*e+1] = m2v[e][1];
    }
    r0 += __shfl_xor(r0, 32);
    #pragma unroll
    for (int d = 0; d < ND; ++d) {
        m1[d] += __shfl_xor(m1[d], 32);
        m2[d] += __shfl_xor(m2[d], 32);
    }
    if (lane < 32) {
        float4* d1 = (float4*)&s_m1[wave][c][0];
        float4* d2 = (float4*)&s_m2[wave][c][0];
        #pragma unroll
        for (int j = 0; j < 4; ++j) {
            d1[sw4(c, j)] = *(const float4*)&m1[4*j];
            d2[sw4(c, j)] = *(const float4*)&m2[4*j];
        }
        s_r0[wave][c] = r0;
    }
    __syncthreads();

    float* my_part = g_part + (size_t)bid * PART_F;
    #pragma unroll 1
    for (int i = t; i < PART_F; i += NTS) {
        float v;
        if (i < NCND) {
            const int cc = i >> 4, d = i & 15;
            const int fi = cc*ND + sw4(cc, d>>2)*4 + (d&3);
            v = (&s_m1[0][0][0])[fi] + (&s_m1[1][0][0])[fi] + (&s_m1[2][0][0])[fi];
        } else if (i < 2*NCND) {
            const int j = i - NCND;
            const int cc = j >> 4, d = j & 15;
            const int fi = cc*ND + sw4(cc, d>>2)*4 + (d&3);
            v = (&s_m2[0][0][0])[fi] + (&s_m2[1][0][0])[fi] + (&s_m2[2][0][0])[fi];
        } else {
            const int cc = i - 2*NCND;
            v = s_r0[0][cc] + s_r0[1][cc] + s_r0[2][cc];
        }
        my_part[i] = v;
    }
}

// =====================================================================
// COMBINE KERNEL: merge the 2 partials -> stats (or final outputs)
// =====================================================================
__global__ __launch_bounds__(512) void convcaps_combine(
    const float* __restrict__ g_part,   // [1152][1056]; halves at bp and bp+576
    float* __restrict__ g_stats,        // [576][1056]
    const float* __restrict__ g_beta_a,
    const float* __restrict__ g_beta_v,
    float* __restrict__ g_out,
    float inv_temp, int last)
{
    __shared__ float sL[NC];
    const int bp = blockIdx.x;
    const int t  = threadIdx.x;         // one (cc,d) item per thread
    const int cc = t >> 4;
    const int d  = t & 15;

    const float* p0 = g_part + (size_t)bp * PART_F;
    const float* p1 = g_part + (size_t)(bp + NBP) * PART_F;

    const float am1 = p0[t] + p1[t];
    const float am2 = p0[NCND + t] + p1[NCND + t];
    const float ar0 = p0[2*NCND + cc] + p1[2*NCND + cc];
    const float rs  = ar0 + EPSI;
    const float irs = __builtin_amdgcn_rcpf(rs);
    const float mu  = am1 * irs;
    // sum rp*(v-mu)^2 = m2 - 2*mu*m1 + mu^2*r0  (exact expansion)
    const float var = (am2 - mu * (2.0f * am1 - mu * ar0)) * irs + EPSI;
    const float lv  = __logf(var);
    const float Ls  = red16_sum(lv);    // d occupies lane bits 0-3
    if (d == 0) sL[cc] = Ls;

    if (!last) {
        float* st = g_stats + (size_t)bp * STATS_F;
        st[t]        = mu;
        st[NCND + t] = __builtin_amdgcn_rcpf(var);
    } else {
        float* outpose = g_out + NBP * NC;
        outpose[(size_t)(bp * NC + cc) * ND + d] = mu;
    }
    __syncthreads();

    if (t < NC) {
        const float log2pi16 = 16.0f * 1.8378770664093453f;
        const float ar0c = p0[2*NCND + t] + p1[2*NCND + t];
        const float rsc  = ar0c + EPSI;
        const float L    = sL[t];
        const float costsum = rsc * (16.0f * g_beta_v[t] + 0.5f * L);
        const float x  = inv_temp * (g_beta_a[t] - costsum);
        const float oa = 1.0f / (1.0f + __expf(-x));
        if (!last) {
            float* st = g_stats + (size_t)bp * STATS_F;
            st[2*NCND + t] = __logf(oa + EPSI) - 0.5f * (log2pi16 + L);
        } else {
            g_out[bp * NC + t] = oa;
        }
    }
}

// =====================================================================
// FALLBACK: r11 verbatim (used when ws_size < WS_NEEDED)
// =====================================================================

__device__ __forceinline__ void reduce_finalize_fb(
    float r0, v2f m1v[NDH], v2f m2v[NDH],
    int t, int c, int wave, int lane, float inv_temp, bool last,
    float rbeta_a, float rbeta_v,
    float (&s_m1)[NRED][NC][ND], float (&s_m2)[NRED][NC][ND], float (&s_r0)[NRED][NC],
    float (&s_mu)[NC][17], float (&s_ivar)[NC][17], float (&s_A)[NC])
{
    float m1[ND], m2[ND];
    #pragma unroll
    for (int e = 0; e < NDH; ++e) {
        m1[2*e] = m1v[e][0]; m1[2*e+1] = m1v[e][1];
        m2[2*e] = m2v[e][0]; m2[2*e+1] = m2v[e][1];
    }
    r0 += __shfl_xor(r0, 32);
    #pragma unroll
    for (int d = 0; d < ND; ++d) {
        m1[d] += __shfl_xor(m1[d], 32);
        m2[d] += __shfl_xor(m2[d], 32);
    }
    if (lane < 32 && wave >= NRED) {
        float4* d1 = (float4*)&s_m1[wave - NRED][c][0];
        float4* d2 = (float4*)&s_m2[wave - NRED][c][0];
        #pragma unroll
        for (int j = 0; j < 4; ++j) {
            d1[sw4(c, j)] = *(const float4*)&m1[4*j];
            d2[sw4(c, j)] = *(const float4*)&m2[4*j];
        }
        s_r0[wave - NRED][c] = r0;
    }
    __syncthreads();
    if (lane < 32 && wave < NRED) {
        float4* d1 = (float4*)&s_m1[wave][c][0];
        float4* d2 = (float4*)&s_m2[wave][c][0];
        #pragma unroll
        for (int j = 0; j < 4; ++j) {
            float4 v1 = d1[sw4(c, j)];
            v1.x += m1[4*j]; v1.y += m1[4*j+1]; v1.z += m1[4*j+2]; v1.w += m1[4*j+3];
            d1[sw4(c, j)] = v1;
            float4 v2 = d2[sw4(c, j)];
            v2.x += m2[4*j]; v2.y += m2[4*j+1]; v2.z += m2[4*j+2]; v2.w += m2[4*j+3];
            d2[sw4(c, j)] = v2;
        }
        s_r0[wave][c] += r0;
    }
    __syncthreads();

    #pragma unroll
    for (int m = 0; m < 2; ++m) {
        const int item = t + m * NT;
        const int cc = item >> 4;
        const int d  = item & 15;
        const int fi = cc * ND + sw4(cc, d >> 2) * 4 + (d & 3);
        const float am1 = (&s_m1[0][0][0])[fi] + (&s_m1[1][0][0])[fi];
        const float am2 = (&s_m2[0][0][0])[fi] + (&s_m2[1][0][0])[fi];
        const float ar0 = s_r0[0][cc] + s_r0[1][cc];
        const float rs  = ar0 + EPSI;
        const float irs = __builtin_amdgcn_rcpf(rs);
        const float mu  = am1 * irs;
        const float var = (am2 - mu * (2.0f * am1 - mu * ar0)) * irs + EPSI;
        const float lv  = __logf(var);
        s_mu[cc][d]   = mu;
        s_ivar[cc][d] = __builtin_amdgcn_rcpf(var);
        const float Ls = red16_sum(lv);
        if (d == 0) s_A[cc] = Ls;
    }
    __syncthreads();

    if (t < NC) {
        const float log2pi16 = 16.0f * 1.8378770664093453f;
        const float ar0 = s_r0[0][t] + s_r0[1][t];
        const float rs = ar0 + EPSI;
        const float L  = s_A[t];
        const float costsum = rs * (16.0f * rbeta_v + 0.5f * L);
        const float x  = inv_temp * (rbeta_a - costsum);
        const float oa = 1.0f / (1.0f + __expf(-x));
        s_A[t] = last ? oa : (__logf(oa + EPSI) - 0.5f * (log2pi16 + L));
    }
    __syncthreads();
}

__global__ __launch_bounds__(NT) void convcaps_em_kernel(
    const float* __restrict__ g_act,
    const float* __restrict__ g_pose,
    const float* __restrict__ g_W,
    const float* __restrict__ g_beta_a,
    const float* __restrict__ g_beta_v,
    const int*   __restrict__ g_cpm,
    float* __restrict__ g_out)
{
    __shared__ float s_pose[NK][ND];
    __shared__ float s_act[NK];
    __shared__ float s_m1[NRED][NC][ND];
    __shared__ float s_m2[NRED][NC][ND];
    __shared__ float s_r0[NRED][NC];
    __shared__ float s_mu[NC][17];
    __shared__ float s_ivar[NC][17];
    __shared__ float s_A[NC];

    const int bp   = blockIdx.x;
    const int b    = bp / NP;
    const int p    = bp - b * NP;
    const int t    = threadIdx.x;
    const int c    = t & 31;
    const int s    = t >> 5;
    const int wave = t >> 6;
    const int lane = t & 63;

    float rbeta_a = 0.0f, rbeta_v = 0.0f;
    if (t < NC) { rbeta_a = g_beta_a[t]; rbeta_v = g_beta_v[t]; }

    {
        const int* cpm = g_cpm + p * KW;
        const float4* pb4 = (const float4*)(g_pose + (size_t)b * (196 * CIN * ND));
        float4* sp4 = (float4*)&s_pose[0][0];
        #pragma unroll 1
        for (int i4 = t; i4 < NK * ND / 4; i4 += NT) {
            const int w   = i4 >> 7;
            const int rem = i4 & 127;
            sp4[i4] = pb4[(size_t)cpm[w] * 128 + rem];
        }
        #pragma unroll 1
        for (int e = t; e < NK; e += NT)
            s_act[e] = g_act[(size_t)b * (196 * CIN) + cpm[e >> 5] * CIN + (e & 31)];
    }
    __syncthreads();

    const int    k0  = s * KPT;
    const float* wp0 = g_W + (size_t)(k0 * NC + c) * ND;

    {
        float r0 = 0.0f;
        v2f m1v[NDH], m2v[NDH];
        #pragma unroll
        for (int d = 0; d < NDH; ++d) { m1v[d] = mkv2(0,0); m2v[d] = mkv2(0,0); }

        const float* wp = wp0;
        #pragma unroll 1
        for (int jj = 0; jj < KPT; jj += 2, wp += 2 * NCND) {
            float pr[ND]; v2f wr[NDH];
            v2f va[NDH], vb[NDH];
            load16(&s_pose[k0 + jj][0], pr);
            load16v(wp, wr);
            vote44v(pr, wr, va);
            load16(&s_pose[k0 + jj + 1][0], pr);
            load16v(wp + NCND, wr);
            vote44v(pr, wr, vb);

            const float2 a2 = *(const float2*)&s_act[k0 + jj];
            const float rpa = a2.x * (1.0f / 32.0f);
            const float rpb = a2.y * (1.0f / 32.0f);
            r0 += rpa + rpb;
            const v2f rpav = mkv2(rpa, rpa), rpbv = mkv2(rpb, rpb);
            #pragma unroll
            for (int d = 0; d < NDH; ++d) {
                const v2f rva = rpav * va[d];
                const v2f rvb = rpbv * vb[d];
                m1v[d] += rva + rvb;
                m2v[d] += rva * va[d] + rvb * vb[d];
            }
        }
        reduce_finalize_fb(r0, m1v, m2v, t, c, wave, lane, 1.0f, false, rbeta_a, rbeta_v,
                           s_m1, s_m2, s_r0, s_mu, s_ivar, s_A);
    }

    #pragma unroll 1
    for (int it = 1; it < 3; ++it) {
        const float L2E = 1.4426950408889634f;
        v2f iv2v[NDH], h2n2v[NDH];
        float gq2 = 0.0f;
        #pragma unroll
        for (int e = 0; e < NDH; ++e) {
            float ivs[2], hns[2];
            #pragma unroll
            for (int u = 0; u < 2; ++u) {
                const float mu  = s_mu[c][2*e+u];
                const float iv2 = s_ivar[c][2*e+u] * (0.5f * L2E);
                ivs[u] = iv2;
                const float h = iv2 * mu;
                hns[u] = -(h + h);
                gq2 = fmaf(h, mu, gq2);
            }
            iv2v[e]  = mkv2(ivs[0], ivs[1]);
            h2n2v[e] = mkv2(hns[0], hns[1]);
        }
        const float A2 = fmaf(L2E, s_A[c], -gq2);

        float r0 = 0.0f;
        v2f m1v[NDH], m2v[NDH];
        #pragma unroll
        for (int d = 0; d < NDH; ++d) { m1v[d] = mkv2(0,0); m2v[d] = mkv2(0,0); }

        const float* wp = wp0;
        #pragma unroll 1
        for (int jj = 0; jj < KPT; jj += 2, wp += 2 * NCND) {
            float pr[ND]; v2f wr[NDH];
            v2f va[NDH], vb[NDH];
            load16(&s_pose[k0 + jj][0], pr);
            load16v(wp, wr);
            vote44v(pr, wr, va);
            load16(&s_pose[k0 + jj + 1][0], pr);
            load16v(wp + NCND, wr);
            vote44v(pr, wr, vb);

            v2f qa2 = mkv2(0,0), qb2 = mkv2(0,0);
            #pragma unroll
            for (int e = 0; e < NDH; ++e) {
                qa2 += (iv2v[e] * va[e] + h2n2v[e]) * va[e];
                qb2 += (iv2v[e] * vb[e] + h2n2v[e]) * vb[e];
            }
            const float la = A2 - (qa2[0] + qa2[1]);
            const float lb = A2 - (qb2[0] + qb2[1]);

            const float ma = red16_max(la);
            const float mb = red16_max(lb);
            const float ea = __builtin_amdgcn_exp2f(la - ma);
            const float eb = __builtin_amdgcn_exp2f(lb - mb);
            const float sa = red16_sum(ea);
            const float sb = red16_sum(eb);
            const float mao = swz16(ma);
            const float sao = swz16(sa);
            const float mbo = swz16(mb);
            const float sbo = swz16(sb);
            const float Ma = fmaxf(ma, mao);
            const float Mb = fmaxf(mb, mbo);
            const float wa = __builtin_amdgcn_exp2f(ma - Ma);
            const float wb = __builtin_amdgcn_exp2f(mb - Mb);
            const float Sa = fmaf(sao, __builtin_amdgcn_exp2f(mao - Ma), sa * wa);
            const float Sb = fmaf(sbo, __builtin_amdgcn_exp2f(mbo - Mb), sb * wb);

            const float2 a2 = *(const float2*)&s_act[k0 + jj];
            const float rpa = ea * wa * __builtin_amdgcn_rcpf(Sa) * a2.x;
            const float rpb = eb * wb * __builtin_amdgcn_rcpf(Sb) * a2.y;
            r0 += rpa + rpb;
            const v2f rpav = mkv2(rpa, rpa), rpbv = mkv2(rpb, rpb);
            #pragma unroll
            for (int d = 0; d < NDH; ++d) {
                const v2f rva = rpav * va[d];
                const v2f rvb = rpbv * vb[d];
                m1v[d] += rva + rvb;
                m2v[d] += rva * va[d] + rvb * vb[d];
            }
        }
        reduce_finalize_fb(r0, m1v, m2v, t, c, wave, lane, 1.0f + (float)it, it == 2,
                           rbeta_a, rbeta_v,
                           s_m1, s_m2, s_r0, s_mu, s_ivar, s_A);
    }

    const int base = bp * NC;
    if (t < NC) g_out[base + t] = s_A[t];
    float* outpose = g_out + NBP * NC;
    #pragma unroll
    for (int m = 0; m < 2; ++m) {
        const int item = t + m * NT;
        const int cc = item >> 4;
        const int d  = item & 15;
        outpose[(size_t)(base + cc) * ND + d] = s_mu[cc][d];
    }
}

extern "C" void kernel_launch(void* const* d_in, const int* in_sizes, int n_in,
                              void* d_out, int out_size, void* d_ws, size_t ws_size,
                              hipStream_t stream) {
    const float* in_act  = (const float*)d_in[0];
    const float* in_pose = (const float*)d_in[1];
    const float* W       = (const float*)d_in[2];
    const float* beta_a  = (const float*)d_in[3];
    const float* beta_v  = (const float*)d_in[4];
    const int*   cpm     = (const int*)d_in[5];
    float* out = (float*)d_out;

    if (ws_size >= WS_NEEDED && d_ws != nullptr) {
        float* part  = (float*)d_ws;
        float* stats = part + WS_PART_FLOATS;
        // pass 0
        convcaps_pass<true><<<dim3(2 * NBP), dim3(NTS), 0, stream>>>(
            in_act, in_pose, W, cpm, stats, part);
        convcaps_combine<<<dim3(NBP), dim3(512), 0, stream>>>(
            part, stats, beta_a, beta_v, out, 1.0f, 0);
        // pass 1
        convcaps_pass<false><<<dim3(2 * NBP), dim3(NTS), 0, stream>>>(
            in_act, in_pose, W, cpm, stats, part);
        convcaps_combine<<<dim3(NBP), dim3(512), 0, stream>>>(
            part, stats, beta_a, beta_v, out, 2.0f, 0);
        // pass 2
        convcaps_pass<false><<<dim3(2 * NBP), dim3(NTS), 0, stream>>>(
            in_act, in_pose, W, cpm, stats, part);
        convcaps_combine<<<dim3(NBP), dim3(512), 0, stream>>>(
            part, stats, beta_a, beta_v, out, 3.0f, 1);
    } else {
        convcaps_em_kernel<<<dim3(NBP), dim3(NT), 0, stream>>>(
            in_act, in_pose, W, beta_a, beta_v, cpm, out);
    }
}

// Round 20
// 97.988 us; speedup vs baseline: 1.1743x; 1.1743x over previous
//
#include <hip/hip_runtime.h>
#include <math.h>

#define NB 4      // batch
#define NP 144    // output spatial positions (12x12)
#define KW 9      // kernel window (3x3)
#define CIN 32
#define NC 32     // output capsules
#define NK 288    // KW*CIN children
#define ND 16     // pose dims
#define NDH 8     // ND/2 (packed float2)
#define NCND 512  // NC*ND
#define EPSI 1e-7f
#define NT 256
#define KPT 36        // k per slice
#define NRED 2        // reduction groups (waves 2-3 write, 0-1 add)

// ============================================================================
// FINAL: r11 restored verbatim — the measured optimum of this op on MI355X.
// 97.7us bench / 106.8us rocprof. 19-round ledger of nulls at this structure:
//   - occupancy x2 (r2 confounded-spill, r13 clean, r19 split-k 2x blocks):
//     null or NEGATIVE — the per-pass floor is parallelism-insensitive.
//   - explicit F/B software pipeline (r12): null (compiler already covers).
//   - DS->VALU softmax exchange (r14 layout-confounded, r16 clean): NEGATIVE.
//   - W register prefetch on this base (r17): null (helped only pre-r11, r8).
//   - packed v2f FP32 (r9): null — CDNA4 vector fp32 == scalar rate.
//   - DPP softmax 10->2 DS ops (r5), unroll-1 I-cache (r10), LDS 58->41->33KB
//     + conflict swizzle (r6): all null.
// Structural ceiling: 3 EM passes are data-dependent (pass i+1 needs pass i's
// mu/var — irreducible); per pass ~33-36us = composite of VALU issue (~15us),
// LDS pipe, L2 W-streaming (589KB W re-read per block), and softmax dependency
// chains that neither TLP (max 4.5 waves/SIMD from the 576-problem grid) nor
// ILP restructuring overlaps further. launch_bounds single-arg ONLY
// (r3/r4: 2nd arg caps VGPR at 256/arg -> catastrophic scratch spill).
// ============================================================================

typedef float v2f __attribute__((ext_vector_type(2)));

__device__ __forceinline__ v2f mkv2(float a, float b) { v2f r; r[0] = a; r[1] = b; return r; }

template<int CTRL>
__device__ __forceinline__ float dppf(float x) {
    return __int_as_float(__builtin_amdgcn_update_dpp(
        0, __float_as_int(x), CTRL, 0xF, 0xF, true));
}
// 0xB1=quad_perm xor1 ; 0x4E=quad_perm xor2 ; 0x141=row_half_mirror (xor4 once
// 4-uniform) ; 0x140=row_mirror (xor8 once 8-uniform)
__device__ __forceinline__ float swz16(float x) {
    return __int_as_float(__builtin_amdgcn_ds_swizzle(__float_as_int(x), 0x401F));
}
__device__ __forceinline__ float red16_max(float x) {
    x = fmaxf(x, dppf<0xB1>(x));
    x = fmaxf(x, dppf<0x4E>(x));
    x = fmaxf(x, dppf<0x141>(x));
    x = fmaxf(x, dppf<0x140>(x));
    return x;
}
__device__ __forceinline__ float red16_sum(float x) {
    x += dppf<0xB1>(x);
    x += dppf<0x4E>(x);
    x += dppf<0x141>(x);
    x += dppf<0x140>(x);
    return x;
}

__device__ __forceinline__ int sw4(int c, int j) { return j ^ ((c >> 1) & 3); }

__device__ __forceinline__ void load16(const float* src, float* dst) {
    const float4* s4 = (const float4*)src;
    *(float4*)&dst[0]  = s4[0];
    *(float4*)&dst[4]  = s4[1];
    *(float4*)&dst[8]  = s4[2];
    *(float4*)&dst[12] = s4[3];
}
__device__ __forceinline__ void load16v(const float* src, v2f* dst) {
    const float4* s4 = (const float4*)src;
    #pragma unroll
    for (int q = 0; q < 4; ++q) {
        const float4 tq = s4[q];
        dst[q*2+0] = mkv2(tq.x, tq.y);
        dst[q*2+1] = mkv2(tq.z, tq.w);
    }
}

// vote pairs: v[i*2+p] = {vote[i*4+2p], vote[i*4+2p+1]}
__device__ __forceinline__ void vote44v(const float* pr, const v2f* wr2, v2f* v) {
    #pragma unroll
    for (int i = 0; i < 4; ++i) {
        const v2f p0 = mkv2(pr[i*4+0], pr[i*4+0]);
        const v2f p1 = mkv2(pr[i*4+1], pr[i*4+1]);
        const v2f p2 = mkv2(pr[i*4+2], pr[i*4+2]);
        const v2f p3 = mkv2(pr[i*4+3], pr[i*4+3]);
        #pragma unroll
        for (int p = 0; p < 2; ++p) {
            v2f acc = p0 * wr2[0*2+p];
            acc += p1 * wr2[1*2+p];
            acc += p2 * wr2[2*2+p];
            acc += p3 * wr2[3*2+p];
            v[i*2+p] = acc;
        }
    }
}

__device__ __forceinline__ void reduce_finalize(
    float r0, v2f m1v[NDH], v2f m2v[NDH],
    int t, int c, int wave, int lane, float inv_temp, bool last,
    float rbeta_a, float rbeta_v,
    float (&s_m1)[NRED][NC][ND], float (&s_m2)[NRED][NC][ND], float (&s_r0)[NRED][NC],
    float (&s_mu)[NC][17], float (&s_ivar)[NC][17], float (&s_A)[NC])
{
    float m1[ND], m2[ND];
    #pragma unroll
    for (int e = 0; e < NDH; ++e) {
        m1[2*e] = m1v[e][0]; m1[2*e+1] = m1v[e][1];
        m2[2*e] = m2v[e][0]; m2[2*e+1] = m2v[e][1];
    }
    // merge the two k-slices within each wave
    r0 += __shfl_xor(r0, 32);
    #pragma unroll
    for (int d = 0; d < ND; ++d) {
        m1[d] += __shfl_xor(m1[d], 32);
        m2[d] += __shfl_xor(m2[d], 32);
    }
    // stage 1: waves 2,3 write groups 0,1 (swizzled float4 -> conflict-free)
    if (lane < 32 && wave >= NRED) {
        float4* d1 = (float4*)&s_m1[wave - NRED][c][0];
        float4* d2 = (float4*)&s_m2[wave - NRED][c][0];
        #pragma unroll
        for (int j = 0; j < 4; ++j) {
            d1[sw4(c, j)] = *(const float4*)&m1[4*j];
            d2[sw4(c, j)] = *(const float4*)&m2[4*j];
        }
        s_r0[wave - NRED][c] = r0;
    }
    __syncthreads();
    // stage 2: waves 0,1 add into their group
    if (lane < 32 && wave < NRED) {
        float4* d1 = (float4*)&s_m1[wave][c][0];
        float4* d2 = (float4*)&s_m2[wave][c][0];
        #pragma unroll
        for (int j = 0; j < 4; ++j) {
            float4 v1 = d1[sw4(c, j)];
            v1.x += m1[4*j]; v1.y += m1[4*j+1]; v1.z += m1[4*j+2]; v1.w += m1[4*j+3];
            d1[sw4(c, j)] = v1;
            float4 v2 = d2[sw4(c, j)];
            v2.x += m2[4*j]; v2.y += m2[4*j+1]; v2.z += m2[4*j+2]; v2.w += m2[4*j+3];
            d2[sw4(c, j)] = v2;
        }
        s_r0[wave][c] += r0;
    }
    __syncthreads();

    // finalize: 512 (cc,d) items over 256 threads -> 2 per thread
    #pragma unroll
    for (int m = 0; m < 2; ++m) {
        const int item = t + m * NT;
        const int cc = item >> 4;
        const int d  = item & 15;
        const int fi = cc * ND + sw4(cc, d >> 2) * 4 + (d & 3);
        const float am1 = (&s_m1[0][0][0])[fi] + (&s_m1[1][0][0])[fi];
        const float am2 = (&s_m2[0][0][0])[fi] + (&s_m2[1][0][0])[fi];
        const float ar0 = s_r0[0][cc] + s_r0[1][cc];
        const float rs  = ar0 + EPSI;
        const float irs = __builtin_amdgcn_rcpf(rs);
        const float mu  = am1 * irs;
        // sum rp*(v-mu)^2 = m2 - 2*mu*m1 + mu^2*r0  (exact expansion)
        const float var = (am2 - mu * (2.0f * am1 - mu * ar0)) * irs + EPSI;
        const float lv  = __logf(var);
        s_mu[cc][d]   = mu;
        s_ivar[cc][d] = __builtin_amdgcn_rcpf(var);
        const float Ls = red16_sum(lv);      // sum over d (lane bits 0-3)
        if (d == 0) s_A[cc] = Ls;            // stash L; consumed below
    }
    __syncthreads();

    if (t < NC) {
        const float log2pi16 = 16.0f * 1.8378770664093453f;
        const float ar0 = s_r0[0][t] + s_r0[1][t];
        const float rs = ar0 + EPSI;
        const float L  = s_A[t];
        const float costsum = rs * (16.0f * rbeta_v + 0.5f * L);
        const float x  = inv_temp * (rbeta_a - costsum);
        const float oa = 1.0f / (1.0f + __expf(-x));
        // last pass: stash oa (the output). otherwise: combined logit base
        s_A[t] = last ? oa : (__logf(oa + EPSI) - 0.5f * (log2pi16 + L));
    }
    __syncthreads();
}

__global__ __launch_bounds__(NT) void convcaps_em_kernel(
    const float* __restrict__ g_act,    // [B,196,32]
    const float* __restrict__ g_pose,   // [B,196,32,16]
    const float* __restrict__ g_W,      // [288,32,16]
    const float* __restrict__ g_beta_a, // [32]
    const float* __restrict__ g_beta_v, // [32]
    const int*   __restrict__ g_cpm,    // [144,9]
    float* __restrict__ g_out)          // act [B*144*32] then pose [B*144*32*16]
{
    __shared__ float s_pose[NK][ND];       // 18432 B
    __shared__ float s_act[NK];            // 1152 B
    __shared__ float s_m1[NRED][NC][ND];   // 4096 B
    __shared__ float s_m2[NRED][NC][ND];   // 4096 B
    __shared__ float s_r0[NRED][NC];       // 256 B
    __shared__ float s_mu[NC][17];         // 2176 B
    __shared__ float s_ivar[NC][17];       // 2176 B
    __shared__ float s_A[NC];              // 128 B   ~= 32.5 KB

    const int bp   = blockIdx.x;
    const int b    = bp / NP;
    const int p    = bp - b * NP;
    const int t    = threadIdx.x;
    const int c    = t & 31;
    const int s    = t >> 5;
    const int wave = t >> 6;
    const int lane = t & 63;

    float rbeta_a = 0.0f, rbeta_v = 0.0f;
    if (t < NC) { rbeta_a = g_beta_a[t]; rbeta_v = g_beta_v[t]; }

    // ---- gather child poses (float4) + activations into LDS ----
    {
        const int* cpm = g_cpm + p * KW;
        const float4* pb4 = (const float4*)(g_pose + (size_t)b * (196 * CIN * ND));
        float4* sp4 = (float4*)&s_pose[0][0];
        #pragma unroll 1
        for (int i4 = t; i4 < NK * ND / 4; i4 += NT) {  // 1152 float4
            const int w   = i4 >> 7;                    // 128 float4 per window
            const int rem = i4 & 127;
            sp4[i4] = pb4[(size_t)cpm[w] * 128 + rem];
        }
        #pragma unroll 1
        for (int e = t; e < NK; e += NT)
            s_act[e] = g_act[(size_t)b * (196 * CIN) + cpm[e >> 5] * CIN + (e & 31)];
    }
    __syncthreads();

    const int    k0  = s * KPT;
    const float* wp0 = g_W + (size_t)(k0 * NC + c) * ND;

    // ================= pass 0: uniform rr = 1/32, 2-k bodies =================
    {
        float r0 = 0.0f;
        v2f m1v[NDH], m2v[NDH];
        #pragma unroll
        for (int d = 0; d < NDH; ++d) { m1v[d] = mkv2(0,0); m2v[d] = mkv2(0,0); }

        const float* wp = wp0;
        #pragma unroll 1
        for (int jj = 0; jj < KPT; jj += 2, wp += 2 * NCND) {
            float pr[ND]; v2f wr[NDH];
            v2f va[NDH], vb[NDH];
            load16(&s_pose[k0 + jj][0], pr);
            load16v(wp, wr);
            vote44v(pr, wr, va);
            load16(&s_pose[k0 + jj + 1][0], pr);
            load16v(wp + NCND, wr);
            vote44v(pr, wr, vb);

            const float2 a2 = *(const float2*)&s_act[k0 + jj];
            const float rpa = a2.x * (1.0f / 32.0f);
            const float rpb = a2.y * (1.0f / 32.0f);
            r0 += rpa + rpb;
            const v2f rpav = mkv2(rpa, rpa), rpbv = mkv2(rpb, rpb);
            #pragma unroll
            for (int d = 0; d < NDH; ++d) {
                const v2f rva = rpav * va[d];
                const v2f rvb = rpbv * vb[d];
                m1v[d] += rva + rvb;
                m2v[d] += rva * va[d] + rvb * vb[d];
            }
        }
        reduce_finalize(r0, m1v, m2v, t, c, wave, lane, 1.0f, false, rbeta_a, rbeta_v,
                        s_m1, s_m2, s_r0, s_mu, s_ivar, s_A);
    }

    // ================= passes 1,2: E-step fused, 2-k interleaved =================
    #pragma unroll 1
    for (int it = 1; it < 3; ++it) {
        // hoist per-iter stats in exp2 domain
        const float L2E = 1.4426950408889634f;
        v2f iv2v[NDH], h2n2v[NDH];
        float gq2 = 0.0f;
        #pragma unroll
        for (int e = 0; e < NDH; ++e) {
            float ivs[2], hns[2];
            #pragma unroll
            for (int u = 0; u < 2; ++u) {
                const float mu  = s_mu[c][2*e+u];
                const float iv2 = s_ivar[c][2*e+u] * (0.5f * L2E);
                ivs[u] = iv2;
                const float h = iv2 * mu;
                hns[u] = -(h + h);
                gq2 = fmaf(h, mu, gq2);
            }
            iv2v[e]  = mkv2(ivs[0], ivs[1]);
            h2n2v[e] = mkv2(hns[0], hns[1]);
        }
        const float A2 = fmaf(L2E, s_A[c], -gq2);

        float r0 = 0.0f;
        v2f m1v[NDH], m2v[NDH];
        #pragma unroll
        for (int d = 0; d < NDH; ++d) { m1v[d] = mkv2(0,0); m2v[d] = mkv2(0,0); }

        const float* wp = wp0;
        #pragma unroll 1
        for (int jj = 0; jj < KPT; jj += 2, wp += 2 * NCND) {
            float pr[ND]; v2f wr[NDH];
            v2f va[NDH], vb[NDH];
            load16(&s_pose[k0 + jj][0], pr);
            load16v(wp, wr);
            vote44v(pr, wr, va);
            load16(&s_pose[k0 + jj + 1][0], pr);
            load16v(wp + NCND, wr);
            vote44v(pr, wr, vb);

            // logits (two independent chains)
            v2f qa2 = mkv2(0,0), qb2 = mkv2(0,0);
            #pragma unroll
            for (int e = 0; e < NDH; ++e) {
                qa2 += (iv2v[e] * va[e] + h2n2v[e]) * va[e];
                qb2 += (iv2v[e] * vb[e] + h2n2v[e]) * vb[e];
            }
            const float la = A2 - (qa2[0] + qa2[1]);
            const float lb = A2 - (qb2[0] + qb2[1]);

            // 16-group max + sum (DPP only), interleaved a/b
            const float ma = red16_max(la);
            const float mb = red16_max(lb);
            const float ea = __builtin_amdgcn_exp2f(la - ma);
            const float eb = __builtin_amdgcn_exp2f(lb - mb);
            const float sa = red16_sum(ea);
            const float sb = red16_sum(eb);
            // exchange (m,s) across xor16: 4 independent swizzles, one wait
            const float mao = swz16(ma);
            const float sao = swz16(sa);
            const float mbo = swz16(mb);
            const float sbo = swz16(sb);
            const float Ma = fmaxf(ma, mao);
            const float Mb = fmaxf(mb, mbo);
            const float wa = __builtin_amdgcn_exp2f(ma - Ma);
            const float wb = __builtin_amdgcn_exp2f(mb - Mb);
            const float Sa = fmaf(sao, __builtin_amdgcn_exp2f(mao - Ma), sa * wa);
            const float Sb = fmaf(sbo, __builtin_amdgcn_exp2f(mbo - Mb), sb * wb);

            const float2 a2 = *(const float2*)&s_act[k0 + jj];
            const float rpa = ea * wa * __builtin_amdgcn_rcpf(Sa) * a2.x;
            const float rpb = eb * wb * __builtin_amdgcn_rcpf(Sb) * a2.y;
            r0 += rpa + rpb;
            const v2f rpav = mkv2(rpa, rpa), rpbv = mkv2(rpb, rpb);
            #pragma unroll
            for (int d = 0; d < NDH; ++d) {
                const v2f rva = rpav * va[d];
                const v2f rvb = rpbv * vb[d];
                m1v[d] += rva + rvb;
                m2v[d] += rva * va[d] + rvb * vb[d];
            }
        }
        reduce_finalize(r0, m1v, m2v, t, c, wave, lane, 1.0f + (float)it, it == 2,
                        rbeta_a, rbeta_v,
                        s_m1, s_m2, s_r0, s_mu, s_ivar, s_A);
    }

    // ---- write outputs: act [B,P,C] then pose [B,P,C,16] ----
    const int base = (b * NP + p) * NC;
    if (t < NC) g_out[base + t] = s_A[t];
    float* outpose = g_out + NB * NP * NC;
    #pragma unroll
    for (int m = 0; m < 2; ++m) {
        const int item = t + m * NT;
        const int cc = item >> 4;
        const int d  = item & 15;
        outpose[(size_t)(base + cc) * ND + d] = s_mu[cc][d];
    }
}

extern "C" void kernel_launch(void* const* d_in, const int* in_sizes, int n_in,
                              void* d_out, int out_size, void* d_ws, size_t ws_size,
                              hipStream_t stream) {
    const float* in_act  = (const float*)d_in[0];
    const float* in_pose = (const float*)d_in[1];
    const float* W       = (const float*)d_in[2];
    const float* beta_a  = (const float*)d_in[3];
    const float* beta_v  = (const float*)d_in[4];
    const int*   cpm     = (const int*)d_in[5];
    float* out = (float*)d_out;

    convcaps_em_kernel<<<dim3(NB * NP), dim3(NT), 0, stream>>>(
        in_act, in_pose, W, beta_a, beta_v, cpm, out);
}